// Round 6
// baseline (326.367 us; speedup 1.0000x reference)
//
#include <hip/hip_runtime.h>
#include <hip/hip_bf16.h>

#define N_GRAPHS 64

typedef __bf16 bf16x8 __attribute__((ext_vector_type(8)));
typedef float floatx4 __attribute__((ext_vector_type(4)));
typedef unsigned short ushort8v __attribute__((ext_vector_type(8)));

__device__ __forceinline__ float b2f(unsigned short u) {
    union { unsigned int i; float f; } v;
    v.i = ((unsigned int)u) << 16;
    return v.f;
}
__device__ __forceinline__ unsigned short f2b(float f) {
    __hip_bfloat16 h = __float2bfloat16(f);
    return *(unsigned short*)&h;
}

// ---------------- CSR build ----------------

__global__ void k_deg(const int* __restrict__ dst, int* __restrict__ deg, int E) {
    int e = blockIdx.x * blockDim.x + threadIdx.x;
    if (e < E) atomicAdd(&deg[dst[e]], 1);
}

__global__ void k_scan_blocks(const int* __restrict__ deg, int* __restrict__ row_start,
                              int* __restrict__ blk_sums, int N) {
    __shared__ int s[256];
    int t = threadIdx.x;
    int i = blockIdx.x * 256 + t;
    int v = (i < N) ? deg[i] : 0;
    s[t] = v;
    __syncthreads();
    for (int off = 1; off < 256; off <<= 1) {
        int x = (t >= off) ? s[t - off] : 0;
        __syncthreads();
        s[t] += x;
        __syncthreads();
    }
    if (i < N) row_start[i] = s[t] - v;  // exclusive within block
    if (t == 255) blk_sums[blockIdx.x] = s[255];
}

__global__ void k_scan_tot(const int* __restrict__ blk_sums, int nb, int* __restrict__ blk_off) {
    __shared__ int s[256];
    int t = threadIdx.x;
    int v = (t < nb) ? blk_sums[t] : 0;
    s[t] = v;
    __syncthreads();
    for (int off = 1; off < 256; off <<= 1) {
        int x = (t >= off) ? s[t - off] : 0;
        __syncthreads();
        s[t] += x;
        __syncthreads();
    }
    if (t < nb) blk_off[t] = s[t] - v;
}

// also computes gstarts (batch is sorted: boundary detection, no atomics)
__global__ void k_scan_add(int* __restrict__ row_start, const int* __restrict__ blk_off,
                           int* __restrict__ cursor, const int* __restrict__ deg,
                           float* __restrict__ dinv, const int* __restrict__ batch,
                           int* __restrict__ gstarts, int N, int E) {
    int i = blockIdx.x * 256 + threadIdx.x;
    if (i < N) {
        int r = row_start[i] + blk_off[blockIdx.x];
        row_start[i] = r;
        cursor[i] = r;
        dinv[i] = 1.0f / sqrtf((float)(deg[i] + 1));  // +1 self-loop
        int b = batch[i];
        int prev = (i == 0) ? -1 : batch[i - 1];
        for (int g = prev + 1; g <= b; ++g) gstarts[g] = i;
        if (i == N - 1)
            for (int g = b + 1; g <= N_GRAPHS; ++g) gstarts[g] = N;
    }
    if (i == 0) row_start[N] = E;
}

// col2[p] = { src, bits(dinv[src]) } — removes the dependent dinv gather from aggregation
__global__ void k_fill(const int* __restrict__ src, const int* __restrict__ dst,
                       int* __restrict__ cursor, int2* __restrict__ col2,
                       const float* __restrict__ dinv, int E) {
    int e = blockIdx.x * blockDim.x + threadIdx.x;
    if (e < E) {
        int s = src[e];
        int p = atomicAdd(&cursor[dst[e]], 1);
        col2[p] = make_int2(s, __float_as_int(dinv[s]));
    }
}

// ------- prep: all 4 weights -> bf16 B-fragment order, plus x -> bf16 padded to 64 ch ------
// frag f = (nt*KS + ks)*64 + lane holds B[k = ks*32 + (lane>>4)*8 + j][n = nt*16 + (lane&15)]
__device__ __forceinline__ void swz_one(const float* __restrict__ W,
                                        unsigned short* __restrict__ Wsw, int i, int K, int Nn,
                                        int KS) {
    int j = i & 7, lane = (i >> 3) & 63;
    int ks = (i >> 9) % KS, nt = i / (512 * KS);
    int n = nt * 16 + (lane & 15);
    int k = ks * 32 + (lane >> 4) * 8 + j;
    float v = (k < K && n < Nn) ? W[(size_t)k * Nn + n] : 0.f;
    Wsw[i] = f2b(v);
}

#define T_W1 (4 * 2 * 512)
#define T_W2 (8 * 2 * 512)
#define T_W3 (14 * 4 * 512)
#define T_WF (13 * 7 * 512)

__global__ void k_prep(const float* __restrict__ W1, const float* __restrict__ W2,
                       const float* __restrict__ W3, const float* __restrict__ Wf,
                       unsigned short* __restrict__ W1s, unsigned short* __restrict__ W2s,
                       unsigned short* __restrict__ W3s, unsigned short* __restrict__ Wfs,
                       const float* __restrict__ x, unsigned short* __restrict__ xb, int Nn) {
    int i = blockIdx.x * 256 + threadIdx.x;
    if (i < T_W1) swz_one(W1, W1s, i, 54, 54, 2);
    else if (i < T_W1 + T_W2) swz_one(W2, W2s, i - T_W1, 54, 108, 2);
    else if (i < T_W1 + T_W2 + T_W3) swz_one(W3, W3s, i - T_W1 - T_W2, 108, 216, 4);
    else if (i < T_W1 + T_W2 + T_W3 + T_WF)
        swz_one(Wf, Wfs, i - T_W1 - T_W2 - T_W3, 216, 200, 7);
    else {
        int ii = i - (T_W1 + T_W2 + T_W3 + T_WF);
        if (ii < Nn * 64) {
            int n = ii >> 6, c = ii & 63;
            xb[ii] = (c < 54) ? f2b(x[(size_t)n * 54 + c]) : (unsigned short)0;
        }
    }
}

// ------- gather-aggregate NODES nodes into LDS (line-aligned padded rows) -------
// agg[n,f] = dinv[n] * ( dinv[n]*in[n,f] + sum_e dinv[src]*in[src,f] )
// P = padded channels (64 or 128). Subgroup of S = P/8 lanes loads one full edge row
// (ushort8 = 16 B/lane). v5: PAIR-INTERLEAVED 4+4 streams — two rows (A,B) processed
// simultaneously, 8 independent row loads in flight per group, halving the serial
// latency-exposure count per wave (R3's 2->4-stream gave -15%; R4 showed extra waves
// don't help; R5 showed the col2 hop was cheap -> the row-load exposure chain is the
// wall). Joint loop runs while both rows have edges; clamped 4-stream tails finish the
// longer row. Tail streams clamp index to re-1 with literal-0 multiplier (no divergence).
// Cross-subgroup reduction via shfl_xor; lanes of subgroup 0 write LDS.

template <int P, int AS, int NODES, int NG>
__device__ __forceinline__ void gatherP(const unsigned short* __restrict__ in,
                                        const int* __restrict__ row_start,
                                        const int2* __restrict__ col2,
                                        const float* __restrict__ dinv,
                                        unsigned short* agg_s, int node0, int N, int t) {
    constexpr int S = P / 8;         // lanes per edge-row
    constexpr int G = 32 / S;        // edges per stream-step per 32-lane group
    constexpr int RPG = NODES / NG;  // rows per group (= 4, even)
    int grp = t >> 5, lane5 = t & 31;
    int j = lane5 / S, cl = lane5 % S;
    int rs_a[RPG], re_a[RPG];
    float dn_a[RPG];
#pragma unroll
    for (int rr = 0; rr < RPG; ++rr) {
        int n = node0 + grp + rr * NG;
        bool valid = n < N;
        rs_a[rr] = valid ? row_start[n] : 0;
        re_a[rr] = valid ? row_start[n + 1] : 0;
        dn_a[rr] = valid ? dinv[n] : 0.f;
    }
#pragma unroll
    for (int pp = 0; pp < RPG; pp += 2) {
        int rA = grp + pp * NG, rB = grp + (pp + 1) * NG;
        int nA = node0 + rA, nB = node0 + rB;
        float aA[8] = {0.f, 0.f, 0.f, 0.f, 0.f, 0.f, 0.f, 0.f};
        float aB[8] = {0.f, 0.f, 0.f, 0.f, 0.f, 0.f, 0.f, 0.f};
        float dnA = dn_a[pp], dnB = dn_a[pp + 1];
        if (j == 0) {
            if (nA < N) {
                ushort8v u = *((const ushort8v*)(in + (size_t)nA * P) + cl);
#pragma unroll
                for (int i = 0; i < 8; ++i) aA[i] = dnA * b2f(u[i]);
            }
            if (nB < N) {
                ushort8v u = *((const ushort8v*)(in + (size_t)nB * P) + cl);
#pragma unroll
                for (int i = 0; i < 8; ++i) aB[i] = dnB * b2f(u[i]);
            }
        }
        int reA = re_a[pp], reB = re_a[pp + 1];
        int eA = rs_a[pp] + j, eB = rs_a[pp + 1] + j;
        // joint loop: 8 independent row loads (4 per row) in flight
        while (eA < reA && eB < reB) {
            int a1 = min(eA + G, reA - 1), a2 = min(eA + 2 * G, reA - 1),
                a3 = min(eA + 3 * G, reA - 1);
            int b1 = min(eB + G, reB - 1), b2 = min(eB + 2 * G, reB - 1),
                b3 = min(eB + 3 * G, reB - 1);
            int2 cA0 = col2[eA], cA1 = col2[a1], cA2 = col2[a2], cA3 = col2[a3];
            int2 cB0 = col2[eB], cB1 = col2[b1], cB2 = col2[b2], cB3 = col2[b3];
            ushort8v vA0 = *((const ushort8v*)(in + (size_t)cA0.x * P) + cl);
            ushort8v vA1 = *((const ushort8v*)(in + (size_t)cA1.x * P) + cl);
            ushort8v vA2 = *((const ushort8v*)(in + (size_t)cA2.x * P) + cl);
            ushort8v vA3 = *((const ushort8v*)(in + (size_t)cA3.x * P) + cl);
            ushort8v vB0 = *((const ushort8v*)(in + (size_t)cB0.x * P) + cl);
            ushort8v vB1 = *((const ushort8v*)(in + (size_t)cB1.x * P) + cl);
            ushort8v vB2 = *((const ushort8v*)(in + (size_t)cB2.x * P) + cl);
            ushort8v vB3 = *((const ushort8v*)(in + (size_t)cB3.x * P) + cl);
            float dA0 = __int_as_float(cA0.y);
            float dA1 = (eA + G < reA) ? __int_as_float(cA1.y) : 0.f;
            float dA2 = (eA + 2 * G < reA) ? __int_as_float(cA2.y) : 0.f;
            float dA3 = (eA + 3 * G < reA) ? __int_as_float(cA3.y) : 0.f;
            float dB0 = __int_as_float(cB0.y);
            float dB1 = (eB + G < reB) ? __int_as_float(cB1.y) : 0.f;
            float dB2 = (eB + 2 * G < reB) ? __int_as_float(cB2.y) : 0.f;
            float dB3 = (eB + 3 * G < reB) ? __int_as_float(cB3.y) : 0.f;
#pragma unroll
            for (int i = 0; i < 8; ++i) {
                aA[i] += dA0 * b2f(vA0[i]) + dA1 * b2f(vA1[i]);
                aA[i] += dA2 * b2f(vA2[i]) + dA3 * b2f(vA3[i]);
                aB[i] += dB0 * b2f(vB0[i]) + dB1 * b2f(vB1[i]);
                aB[i] += dB2 * b2f(vB2[i]) + dB3 * b2f(vB3[i]);
            }
            eA += 4 * G;
            eB += 4 * G;
        }
        // tails: at most one of these typically runs (deg variance is small)
        for (; eA < reA; eA += 4 * G) {
            int a1 = min(eA + G, reA - 1), a2 = min(eA + 2 * G, reA - 1),
                a3 = min(eA + 3 * G, reA - 1);
            int2 c0 = col2[eA], c1 = col2[a1], c2 = col2[a2], c3 = col2[a3];
            ushort8v v0 = *((const ushort8v*)(in + (size_t)c0.x * P) + cl);
            ushort8v v1 = *((const ushort8v*)(in + (size_t)c1.x * P) + cl);
            ushort8v v2 = *((const ushort8v*)(in + (size_t)c2.x * P) + cl);
            ushort8v v3 = *((const ushort8v*)(in + (size_t)c3.x * P) + cl);
            float d0 = __int_as_float(c0.y);
            float d1 = (eA + G < reA) ? __int_as_float(c1.y) : 0.f;
            float d2 = (eA + 2 * G < reA) ? __int_as_float(c2.y) : 0.f;
            float d3 = (eA + 3 * G < reA) ? __int_as_float(c3.y) : 0.f;
#pragma unroll
            for (int i = 0; i < 8; ++i) {
                aA[i] += d0 * b2f(v0[i]) + d1 * b2f(v1[i]);
                aA[i] += d2 * b2f(v2[i]) + d3 * b2f(v3[i]);
            }
        }
        for (; eB < reB; eB += 4 * G) {
            int b1 = min(eB + G, reB - 1), b2 = min(eB + 2 * G, reB - 1),
                b3 = min(eB + 3 * G, reB - 1);
            int2 c0 = col2[eB], c1 = col2[b1], c2 = col2[b2], c3 = col2[b3];
            ushort8v v0 = *((const ushort8v*)(in + (size_t)c0.x * P) + cl);
            ushort8v v1 = *((const ushort8v*)(in + (size_t)c1.x * P) + cl);
            ushort8v v2 = *((const ushort8v*)(in + (size_t)c2.x * P) + cl);
            ushort8v v3 = *((const ushort8v*)(in + (size_t)c3.x * P) + cl);
            float d0 = __int_as_float(c0.y);
            float d1 = (eB + G < reB) ? __int_as_float(c1.y) : 0.f;
            float d2 = (eB + 2 * G < reB) ? __int_as_float(c2.y) : 0.f;
            float d3 = (eB + 3 * G < reB) ? __int_as_float(c3.y) : 0.f;
#pragma unroll
            for (int i = 0; i < 8; ++i) {
                aB[i] += d0 * b2f(v0[i]) + d1 * b2f(v1[i]);
                aB[i] += d2 * b2f(v2[i]) + d3 * b2f(v3[i]);
            }
        }
#pragma unroll
        for (int i = 0; i < 8; ++i) {
            aA[i] *= dnA;
            aB[i] *= dnB;
        }
        // reduce partial sums across subgroups (same channels at lane ^ S, ^2S, ...)
#pragma unroll
        for (int mask = S; mask < 32; mask <<= 1)
#pragma unroll
            for (int i = 0; i < 8; ++i) {
                aA[i] += __shfl_xor(aA[i], mask, 32);
                aB[i] += __shfl_xor(aB[i], mask, 32);
            }
        if (j == 0) {
            ushort8v rvA, rvB;
#pragma unroll
            for (int i = 0; i < 8; ++i) {
                rvA[i] = f2b(aA[i]);
                rvB[i] = f2b(aB[i]);
            }
            *((ushort8v*)(agg_s + rA * AS) + cl) = rvA;
            *((ushort8v*)(agg_s + rB * AS) + cl) = rvB;
        }
    }
}

// ------- fused GCN layer: gather-agg (LDS) -> MFMA @W + bias + relu -> bf16 h (padded) ----
// 16 nodes/block, 128 threads (2 waves): measured better than 32/256 for these layers (R4).
// A-frag: A[m=lane&15][k=(lane>>4)*8+j]; C/D: col=lane&15, row=(lane>>4)*4+reg (m89/m91).
// W pre-swizzled (k_prep).

template <int P, int FOUT, int FP, int KS, int NT>
__global__ __launch_bounds__(128) void k_layer(
    const unsigned short* __restrict__ in, const int* __restrict__ row_start,
    const int2* __restrict__ col2, const float* __restrict__ dinv,
    const unsigned short* __restrict__ Wsw, const float* __restrict__ bias,
    unsigned short* __restrict__ hout, int N) {
    constexpr int AS = KS * 32 + 8;
    __shared__ __align__(16) unsigned short agg_s[16 * AS];
    int node0 = blockIdx.x * 16;
    int t = threadIdx.x;
    gatherP<P, AS, 16, 4>(in, row_start, col2, dinv, agg_s, node0, N, t);
    __syncthreads();
    int lane = t & 63, wv = t >> 6, m = lane & 15, q = lane >> 4;
    bf16x8 a[KS];
#pragma unroll
    for (int ks = 0; ks < KS; ++ks)
        a[ks] = *(const bf16x8*)(agg_s + m * AS + ks * 32 + q * 8);
    for (int nt = wv; nt < NT; nt += 2) {
        const unsigned short* bp = Wsw + ((size_t)(nt * KS) * 64 + lane) * 8;
        bf16x8 bfr[KS];
#pragma unroll
        for (int ks = 0; ks < KS; ++ks) bfr[ks] = *(const bf16x8*)(bp + ks * 512);
        int fo = nt * 16 + m;
        float bb = (fo < FOUT) ? bias[fo] : 0.f;
        floatx4 c = {0.f, 0.f, 0.f, 0.f};
#pragma unroll
        for (int ks = 0; ks < KS; ++ks)
            c = __builtin_amdgcn_mfma_f32_16x16x32_bf16(a[ks], bfr[ks], c, 0, 0, 0);
#pragma unroll
        for (int r = 0; r < 4; ++r) {
            int n = node0 + q * 4 + r;
            if (n < N) hout[(size_t)n * FP + fo] = f2b(fmaxf(c[r] + bb, 0.f));
        }
    }
}

// -------- fused: gather-agg(h2) -> h3 = relu(@W3+b3) -> out = h3@Wf+bf -> dense batch ----
// 32 nodes/block, 256 threads (best measured geometry, R3). agg_s/h3_s unioned (14.5 KB);
// barrier protects the overlap.

__global__ __launch_bounds__(256) void k_l3f(
    const unsigned short* __restrict__ h2, const int* __restrict__ row_start,
    const int2* __restrict__ col2, const float* __restrict__ dinv,
    const unsigned short* __restrict__ W3s, const float* __restrict__ b3,
    const unsigned short* __restrict__ Wfs, const float* __restrict__ bfv,
    const int* __restrict__ batch, const int* __restrict__ gstarts, float* __restrict__ out,
    int N, int mn) {
    constexpr int AS = 136, HS = 232;
    __shared__ __align__(16) unsigned short smem[32 * HS];  // 14.5 KB, agg/h3 unioned
    unsigned short* agg_s = smem;
    unsigned short* h3_s = smem;
    int node0 = blockIdx.x * 32;
    int t = threadIdx.x;
    gatherP<128, AS, 32, 8>(h2, row_start, col2, dinv, agg_s, node0, N, t);
    __syncthreads();
    int lane = t & 63, wv = t >> 6, m = lane & 15, q = lane >> 4;
    // phase-1 A-frags: 2 m-tiles x 4 k-steps (K = 128 padded)
    bf16x8 a1[2][4];
#pragma unroll
    for (int mt = 0; mt < 2; ++mt)
#pragma unroll
        for (int ks = 0; ks < 4; ++ks)
            a1[mt][ks] = *(const bf16x8*)(agg_s + (mt * 16 + m) * AS + ks * 32 + q * 8);
    __syncthreads();  // all agg_s reads done before h3_s overwrites the same LDS
    // phase 1: h3(216, pad 224) = relu(agg @ W3 + b3)
    for (int nt = wv; nt < 14; nt += 4) {
        const unsigned short* bp = W3s + ((size_t)(nt * 4) * 64 + lane) * 8;
        bf16x8 bf0 = *(const bf16x8*)(bp);
        bf16x8 bf1 = *(const bf16x8*)(bp + 512);
        bf16x8 bf2 = *(const bf16x8*)(bp + 1024);
        bf16x8 bf3 = *(const bf16x8*)(bp + 1536);
        int fo = nt * 16 + m;
        float bb = (fo < 216) ? b3[fo] : 0.f;
#pragma unroll
        for (int mt = 0; mt < 2; ++mt) {
            floatx4 c = {0.f, 0.f, 0.f, 0.f};
            c = __builtin_amdgcn_mfma_f32_16x16x32_bf16(a1[mt][0], bf0, c, 0, 0, 0);
            c = __builtin_amdgcn_mfma_f32_16x16x32_bf16(a1[mt][1], bf1, c, 0, 0, 0);
            c = __builtin_amdgcn_mfma_f32_16x16x32_bf16(a1[mt][2], bf2, c, 0, 0, 0);
            c = __builtin_amdgcn_mfma_f32_16x16x32_bf16(a1[mt][3], bf3, c, 0, 0, 0);
#pragma unroll
            for (int r = 0; r < 4; ++r) {
                int row = mt * 16 + q * 4 + r;
                h3_s[row * HS + fo] = f2b(fmaxf(c[r] + bb, 0.f));
            }
        }
    }
    __syncthreads();
    // phase-2 A-frags: 2 m-tiles x 7 k-steps (K pad 216->224; cols 216..223 are 0)
    bf16x8 a2[2][7];
#pragma unroll
    for (int mt = 0; mt < 2; ++mt)
#pragma unroll
        for (int ks = 0; ks < 7; ++ks)
            a2[mt][ks] = *(const bf16x8*)(h3_s + (mt * 16 + m) * HS + ks * 32 + q * 8);
    // phase 2: out(200) = h3 @ Wf + bf -> dense batch scatter
    for (int nt = wv; nt < 13; nt += 4) {
        const unsigned short* bp = Wfs + ((size_t)(nt * 7) * 64 + lane) * 8;
        bf16x8 bfr[7];
#pragma unroll
        for (int ks = 0; ks < 7; ++ks) bfr[ks] = *(const bf16x8*)(bp + ks * 512);
        int fo = nt * 16 + m;
        if (fo >= 200) continue;
        float bb = bfv[fo];
#pragma unroll
        for (int mt = 0; mt < 2; ++mt) {
            floatx4 c = {0.f, 0.f, 0.f, 0.f};
#pragma unroll
            for (int ks = 0; ks < 7; ++ks)
                c = __builtin_amdgcn_mfma_f32_16x16x32_bf16(a2[mt][ks], bfr[ks], c, 0, 0, 0);
#pragma unroll
            for (int r = 0; r < 4; ++r) {
                int n = node0 + mt * 16 + q * 4 + r;
                if (n < N) {
                    int b = batch[n];
                    int pos = n - gstarts[b];
                    if (pos >= 0 && pos < mn)
                        out[((size_t)b * mn + pos) * 200 + fo] = c[r] + bb;
                }
            }
        }
    }
}

extern "C" void kernel_launch(void* const* d_in, const int* in_sizes, int n_in,
                              void* d_out, int out_size, void* d_ws, size_t ws_size,
                              hipStream_t stream) {
    const float* x = (const float*)d_in[0];
    const int* ei = (const int*)d_in[1];
    const int* batch = (const int*)d_in[2];
    const float* W1 = (const float*)d_in[4];
    const float* b1 = (const float*)d_in[5];
    const float* W2 = (const float*)d_in[6];
    const float* b2 = (const float*)d_in[7];
    const float* W3 = (const float*)d_in[8];
    const float* b3 = (const float*)d_in[9];
    const float* Wf = (const float*)d_in[10];
    const float* bfv = (const float*)d_in[11];
    float* out = (float*)d_out;

    const int N = in_sizes[2];      // 50000
    const int E = in_sizes[1] / 2;  // 800000
    const int mn = out_size / (N_GRAPHS * 200);  // max_num = 1000
    const int* src = ei;
    const int* dst = ei + E;

    char* w = (char*)d_ws;  // ws is 256 MiB (observed via harness poison fills)
    auto alloc = [&](size_t bytes) {
        void* p = (void*)w;
        w += (bytes + 255) & ~(size_t)255;
        return p;
    };
    int* deg = (int*)alloc((size_t)N * 4);
    int* row_start = (int*)alloc((size_t)(N + 1) * 4);
    int* blk_sums = (int*)alloc(256 * 4);
    int* blk_off = (int*)alloc(256 * 4);
    int* cursor = (int*)alloc((size_t)N * 4);
    int2* col2 = (int2*)alloc((size_t)E * 8);
    float* dinv = (float*)alloc((size_t)N * 4);
    int* gstarts = (int*)alloc((N_GRAPHS + 1) * 4);
    unsigned short* xb = (unsigned short*)alloc((size_t)N * 64 * 2);   // padded, line-aligned
    unsigned short* h1 = (unsigned short*)alloc((size_t)N * 64 * 2);   // padded
    unsigned short* h2 = (unsigned short*)alloc((size_t)N * 128 * 2);  // padded
    unsigned short* W1s = (unsigned short*)alloc((size_t)T_W1 * 2);
    unsigned short* W2s = (unsigned short*)alloc((size_t)T_W2 * 2);
    unsigned short* W3s = (unsigned short*)alloc((size_t)T_W3 * 2);
    unsigned short* Wfs = (unsigned short*)alloc((size_t)T_WF * 2);
    (void)ws_size;

    hipMemsetAsync(deg, 0, (size_t)N * 4, stream);
    hipMemsetAsync(d_out, 0, (size_t)out_size * sizeof(float), stream);

    int NB = (N + 255) / 256;  // 196 <= 256, single-level block scan OK
    k_deg<<<(E + 255) / 256, 256, 0, stream>>>(dst, deg, E);
    k_scan_blocks<<<NB, 256, 0, stream>>>(deg, row_start, blk_sums, N);
    k_scan_tot<<<1, 256, 0, stream>>>(blk_sums, NB, blk_off);
    k_scan_add<<<NB, 256, 0, stream>>>(row_start, blk_off, cursor, deg, dinv, batch, gstarts,
                                       N, E);
    k_fill<<<(E + 255) / 256, 256, 0, stream>>>(src, dst, cursor, col2, dinv, E);
    int prep_total = T_W1 + T_W2 + T_W3 + T_WF + N * 64;
    k_prep<<<(prep_total + 255) / 256, 256, 0, stream>>>(W1, W2, W3, Wf, W1s, W2s, W3s, Wfs,
                                                         x, xb, N);

    int NBL16 = (N + 15) / 16;  // 128-thread blocks for the two light layers (R4 win)
    // layer 1: gather(xb, 64p) -> MFMA @W1 -> h1[64p]
    k_layer<64, 54, 64, 2, 4><<<NBL16, 128, 0, stream>>>(xb, row_start, col2, dinv, W1s, b1,
                                                         h1, N);
    // layer 2: gather(h1, 64p) -> MFMA @W2 -> h2[128p]
    k_layer<64, 108, 128, 2, 8><<<NBL16, 128, 0, stream>>>(h1, row_start, col2, dinv, W2s,
                                                           b2, h2, N);
    int NBL32 = (N + 31) / 32;  // 256-thread blocks for the heavy fused kernel (R3 win)
    // layer 3 + final: gather(h2, 128p) -> MFMA @W3 relu -> MFMA @Wf -> dense-batch scatter
    k_l3f<<<NBL32, 256, 0, stream>>>(h2, row_start, col2, dinv, W3s, b3, Wfs, bfv, batch,
                                     gstarts, out, N, mn);
}

// Round 8
// 300.570 us; speedup vs baseline: 1.0858x; 1.0858x over previous
//
#include <hip/hip_runtime.h>
#include <hip/hip_bf16.h>

#define N_GRAPHS 64

typedef __bf16 bf16x8 __attribute__((ext_vector_type(8)));
typedef float floatx4 __attribute__((ext_vector_type(4)));
typedef unsigned short ushort8v __attribute__((ext_vector_type(8)));

__device__ __forceinline__ float b2f(unsigned short u) {
    union { unsigned int i; float f; } v;
    v.i = ((unsigned int)u) << 16;
    return v.f;
}
__device__ __forceinline__ unsigned short f2b(float f) {
    __hip_bfloat16 h = __float2bfloat16(f);
    return *(unsigned short*)&h;
}

// ---------------- CSR build ----------------

__global__ void k_deg(const int* __restrict__ dst, int* __restrict__ deg, int E) {
    int e = blockIdx.x * blockDim.x + threadIdx.x;
    if (e < E) atomicAdd(&deg[dst[e]], 1);
}

__global__ void k_scan_blocks(const int* __restrict__ deg, int* __restrict__ row_start,
                              int* __restrict__ blk_sums, int N) {
    __shared__ int s[256];
    int t = threadIdx.x;
    int i = blockIdx.x * 256 + t;
    int v = (i < N) ? deg[i] : 0;
    s[t] = v;
    __syncthreads();
    for (int off = 1; off < 256; off <<= 1) {
        int x = (t >= off) ? s[t - off] : 0;
        __syncthreads();
        s[t] += x;
        __syncthreads();
    }
    if (i < N) row_start[i] = s[t] - v;  // exclusive within block
    if (t == 255) blk_sums[blockIdx.x] = s[255];
}

__global__ void k_scan_tot(const int* __restrict__ blk_sums, int nb, int* __restrict__ blk_off) {
    __shared__ int s[256];
    int t = threadIdx.x;
    int v = (t < nb) ? blk_sums[t] : 0;
    s[t] = v;
    __syncthreads();
    for (int off = 1; off < 256; off <<= 1) {
        int x = (t >= off) ? s[t - off] : 0;
        __syncthreads();
        s[t] += x;
        __syncthreads();
    }
    if (t < nb) blk_off[t] = s[t] - v;
}

// also computes gstarts (batch is sorted: boundary detection, no atomics)
__global__ void k_scan_add(int* __restrict__ row_start, const int* __restrict__ blk_off,
                           int* __restrict__ cursor, const int* __restrict__ deg,
                           float* __restrict__ dinv, const int* __restrict__ batch,
                           int* __restrict__ gstarts, int N, int E) {
    int i = blockIdx.x * 256 + threadIdx.x;
    if (i < N) {
        int r = row_start[i] + blk_off[blockIdx.x];
        row_start[i] = r;
        cursor[i] = r;
        dinv[i] = 1.0f / sqrtf((float)(deg[i] + 1));  // +1 self-loop
        int b = batch[i];
        int prev = (i == 0) ? -1 : batch[i - 1];
        for (int g = prev + 1; g <= b; ++g) gstarts[g] = i;
        if (i == N - 1)
            for (int g = b + 1; g <= N_GRAPHS; ++g) gstarts[g] = N;
    }
    if (i == 0) row_start[N] = E;
}

// col2[p] = { src, bits(dinv[src]) } — removes the dependent dinv gather from aggregation
__global__ void k_fill(const int* __restrict__ src, const int* __restrict__ dst,
                       int* __restrict__ cursor, int2* __restrict__ col2,
                       const float* __restrict__ dinv, int E) {
    int e = blockIdx.x * blockDim.x + threadIdx.x;
    if (e < E) {
        int s = src[e];
        int p = atomicAdd(&cursor[dst[e]], 1);
        col2[p] = make_int2(s, __float_as_int(dinv[s]));
    }
}

// ------- prep: all 4 weights -> bf16 B-fragment order, plus x -> bf16 padded to 64 ch ------
// frag f = (nt*KS + ks)*64 + lane holds B[k = ks*32 + (lane>>4)*8 + j][n = nt*16 + (lane&15)]
__device__ __forceinline__ void swz_one(const float* __restrict__ W,
                                        unsigned short* __restrict__ Wsw, int i, int K, int Nn,
                                        int KS) {
    int j = i & 7, lane = (i >> 3) & 63;
    int ks = (i >> 9) % KS, nt = i / (512 * KS);
    int n = nt * 16 + (lane & 15);
    int k = ks * 32 + (lane >> 4) * 8 + j;
    float v = (k < K && n < Nn) ? W[(size_t)k * Nn + n] : 0.f;
    Wsw[i] = f2b(v);
}

#define T_W1 (4 * 2 * 512)
#define T_W2 (8 * 2 * 512)
#define T_W3 (14 * 4 * 512)
#define T_WF (13 * 7 * 512)

__global__ void k_prep(const float* __restrict__ W1, const float* __restrict__ W2,
                       const float* __restrict__ W3, const float* __restrict__ Wf,
                       unsigned short* __restrict__ W1s, unsigned short* __restrict__ W2s,
                       unsigned short* __restrict__ W3s, unsigned short* __restrict__ Wfs,
                       const float* __restrict__ x, unsigned short* __restrict__ xb, int Nn) {
    int i = blockIdx.x * 256 + threadIdx.x;
    if (i < T_W1) swz_one(W1, W1s, i, 54, 54, 2);
    else if (i < T_W1 + T_W2) swz_one(W2, W2s, i - T_W1, 54, 108, 2);
    else if (i < T_W1 + T_W2 + T_W3) swz_one(W3, W3s, i - T_W1 - T_W2, 108, 216, 4);
    else if (i < T_W1 + T_W2 + T_W3 + T_WF)
        swz_one(Wf, Wfs, i - T_W1 - T_W2 - T_W3, 216, 200, 7);
    else {
        int ii = i - (T_W1 + T_W2 + T_W3 + T_WF);
        if (ii < Nn * 64) {
            int n = ii >> 6, c = ii & 63;
            xb[ii] = (c < 54) ? f2b(x[(size_t)n * 54 + c]) : (unsigned short)0;
        }
    }
}

// ------- gather-aggregate NODES nodes into LDS (line-aligned padded rows) -------
// agg[n,f] = dinv[n] * ( dinv[n]*in[n,f] + sum_e dinv[src]*in[src,f] )
// P = padded channels (64 or 128). Subgroup of S = P/8 lanes loads one full edge row
// (ushort8 = 16 B/lane). Predicated 4-stream inner loop (4 independent row loads in
// flight; tail indices clamped to re-1 with literal-0 multiplier). Row bounds + dinv
// hoisted. RPG = NODES/NG = 2: waves-per-node-tile doubled at identical per-block
// weight traffic (R3..R6: time tracks resident waves; latency-bound). NO min-waves
// launch_bounds: present in both NaN failures (R1, R7), absent in all passes —
// forced-VGPR spills miscompile/misbehave under this harness. Cross-subgroup
// reduction via shfl_xor; lanes of subgroup 0 write LDS.

template <int P, int AS, int NODES, int NG>
__device__ __forceinline__ void gatherP(const unsigned short* __restrict__ in,
                                        const int* __restrict__ row_start,
                                        const int2* __restrict__ col2,
                                        const float* __restrict__ dinv,
                                        unsigned short* agg_s, int node0, int N, int t) {
    constexpr int S = P / 8;         // lanes per edge-row
    constexpr int G = 32 / S;        // edges per stream-step per 32-lane group
    constexpr int RPG = NODES / NG;  // rows per group (= 2)
    int grp = t >> 5, lane5 = t & 31;
    int j = lane5 / S, cl = lane5 % S;
    int rs_a[RPG], re_a[RPG];
    float dn_a[RPG];
#pragma unroll
    for (int rr = 0; rr < RPG; ++rr) {
        int n = node0 + grp + rr * NG;
        bool valid = n < N;
        rs_a[rr] = valid ? row_start[n] : 0;
        re_a[rr] = valid ? row_start[n + 1] : 0;
        dn_a[rr] = valid ? dinv[n] : 0.f;
    }
#pragma unroll
    for (int rr = 0; rr < RPG; ++rr) {
        int r = grp + rr * NG;
        int n = node0 + r;
        float a[8] = {0.f, 0.f, 0.f, 0.f, 0.f, 0.f, 0.f, 0.f};
        if (n < N) {
            float dn = dn_a[rr];
            if (j == 0) {
                ushort8v u = *((const ushort8v*)(in + (size_t)n * P) + cl);
#pragma unroll
                for (int i = 0; i < 8; ++i) a[i] = dn * b2f(u[i]);
            }
            int re = re_a[rr];
            int e = rs_a[rr] + j;
            for (; e < re; e += 4 * G) {
                int e1 = min(e + G, re - 1);
                int e2 = min(e + 2 * G, re - 1);
                int e3 = min(e + 3 * G, re - 1);
                int2 c0 = col2[e];
                int2 c1 = col2[e1];
                int2 c2 = col2[e2];
                int2 c3 = col2[e3];
                ushort8v v0 = *((const ushort8v*)(in + (size_t)c0.x * P) + cl);
                ushort8v v1 = *((const ushort8v*)(in + (size_t)c1.x * P) + cl);
                ushort8v v2 = *((const ushort8v*)(in + (size_t)c2.x * P) + cl);
                ushort8v v3 = *((const ushort8v*)(in + (size_t)c3.x * P) + cl);
                float d0 = __int_as_float(c0.y);
                float d1 = (e + G < re) ? __int_as_float(c1.y) : 0.f;
                float d2 = (e + 2 * G < re) ? __int_as_float(c2.y) : 0.f;
                float d3 = (e + 3 * G < re) ? __int_as_float(c3.y) : 0.f;
#pragma unroll
                for (int i = 0; i < 8; ++i) {
                    a[i] += d0 * b2f(v0[i]) + d1 * b2f(v1[i]);
                    a[i] += d2 * b2f(v2[i]) + d3 * b2f(v3[i]);
                }
            }
#pragma unroll
            for (int i = 0; i < 8; ++i) a[i] *= dn;
        }
        // reduce partial sums across subgroups (same channels at lane ^ S, ^2S, ...)
#pragma unroll
        for (int mask = S; mask < 32; mask <<= 1)
#pragma unroll
            for (int i = 0; i < 8; ++i) a[i] += __shfl_xor(a[i], mask, 32);
        if (j == 0) {
            ushort8v rv;
#pragma unroll
            for (int i = 0; i < 8; ++i) rv[i] = f2b(a[i]);
            *((ushort8v*)(agg_s + r * AS) + cl) = rv;
        }
    }
}

// ------- fused GCN layer: gather-agg (LDS) -> MFMA @W + bias + relu -> bf16 h (padded) ----
// 16 nodes/block, 256 threads (4 waves, NG=8, RPG=2). Same block count / weight traffic
// as the R4-best 128t config, double the waves. A-frag: A[m=lane&15][k=(lane>>4)*8+j];
// C/D: col=lane&15, row=(lane>>4)*4+reg (m89/m91). W pre-swizzled (k_prep).

template <int P, int FOUT, int FP, int KS, int NT>
__global__ __launch_bounds__(256) void k_layer(
    const unsigned short* __restrict__ in, const int* __restrict__ row_start,
    const int2* __restrict__ col2, const float* __restrict__ dinv,
    const unsigned short* __restrict__ Wsw, const float* __restrict__ bias,
    unsigned short* __restrict__ hout, int N) {
    constexpr int AS = KS * 32 + 8;
    __shared__ __align__(16) unsigned short agg_s[16 * AS];
    int node0 = blockIdx.x * 16;
    int t = threadIdx.x;
    gatherP<P, AS, 16, 8>(in, row_start, col2, dinv, agg_s, node0, N, t);
    __syncthreads();
    int lane = t & 63, wv = t >> 6, m = lane & 15, q = lane >> 4;
    bf16x8 a[KS];
#pragma unroll
    for (int ks = 0; ks < KS; ++ks)
        a[ks] = *(const bf16x8*)(agg_s + m * AS + ks * 32 + q * 8);
    for (int nt = wv; nt < NT; nt += 4) {
        const unsigned short* bp = Wsw + ((size_t)(nt * KS) * 64 + lane) * 8;
        bf16x8 bfr[KS];
#pragma unroll
        for (int ks = 0; ks < KS; ++ks) bfr[ks] = *(const bf16x8*)(bp + ks * 512);
        int fo = nt * 16 + m;
        float bb = (fo < FOUT) ? bias[fo] : 0.f;
        floatx4 c = {0.f, 0.f, 0.f, 0.f};
#pragma unroll
        for (int ks = 0; ks < KS; ++ks)
            c = __builtin_amdgcn_mfma_f32_16x16x32_bf16(a[ks], bfr[ks], c, 0, 0, 0);
#pragma unroll
        for (int r = 0; r < 4; ++r) {
            int n = node0 + q * 4 + r;
            if (n < N) hout[(size_t)n * FP + fo] = f2b(fmaxf(c[r] + bb, 0.f));
        }
    }
}

// -------- fused: gather-agg(h2) -> h3 = relu(@W3+b3) -> out = h3@Wf+bf -> dense batch ----
// 32 nodes/block, 512 threads (8 waves, NG=16, RPG=2). Same 1563 blocks / weight traffic
// as R3-best, double the waves. agg_s/h3_s unioned (14.5 KB); barrier protects overlap.

__global__ __launch_bounds__(512) void k_l3f(
    const unsigned short* __restrict__ h2, const int* __restrict__ row_start,
    const int2* __restrict__ col2, const float* __restrict__ dinv,
    const unsigned short* __restrict__ W3s, const float* __restrict__ b3,
    const unsigned short* __restrict__ Wfs, const float* __restrict__ bfv,
    const int* __restrict__ batch, const int* __restrict__ gstarts, float* __restrict__ out,
    int N, int mn) {
    constexpr int AS = 136, HS = 232;
    __shared__ __align__(16) unsigned short smem[32 * HS];  // 14.5 KB, agg/h3 unioned
    unsigned short* agg_s = smem;
    unsigned short* h3_s = smem;
    int node0 = blockIdx.x * 32;
    int t = threadIdx.x;
    gatherP<128, AS, 32, 16>(h2, row_start, col2, dinv, agg_s, node0, N, t);
    __syncthreads();
    int lane = t & 63, wv = t >> 6, m = lane & 15, q = lane >> 4;
    // phase-1 A-frags: 2 m-tiles x 4 k-steps (K = 128 padded)
    bf16x8 a1[2][4];
#pragma unroll
    for (int mt = 0; mt < 2; ++mt)
#pragma unroll
        for (int ks = 0; ks < 4; ++ks)
            a1[mt][ks] = *(const bf16x8*)(agg_s + (mt * 16 + m) * AS + ks * 32 + q * 8);
    __syncthreads();  // all agg_s reads done before h3_s overwrites the same LDS
    // phase 1: h3(216, pad 224) = relu(agg @ W3 + b3); 8 waves cover nt 0..13
    for (int nt = wv; nt < 14; nt += 8) {
        const unsigned short* bp = W3s + ((size_t)(nt * 4) * 64 + lane) * 8;
        bf16x8 bf0 = *(const bf16x8*)(bp);
        bf16x8 bf1 = *(const bf16x8*)(bp + 512);
        bf16x8 bf2 = *(const bf16x8*)(bp + 1024);
        bf16x8 bf3 = *(const bf16x8*)(bp + 1536);
        int fo = nt * 16 + m;
        float bb = (fo < 216) ? b3[fo] : 0.f;
#pragma unroll
        for (int mt = 0; mt < 2; ++mt) {
            floatx4 c = {0.f, 0.f, 0.f, 0.f};
            c = __builtin_amdgcn_mfma_f32_16x16x32_bf16(a1[mt][0], bf0, c, 0, 0, 0);
            c = __builtin_amdgcn_mfma_f32_16x16x32_bf16(a1[mt][1], bf1, c, 0, 0, 0);
            c = __builtin_amdgcn_mfma_f32_16x16x32_bf16(a1[mt][2], bf2, c, 0, 0, 0);
            c = __builtin_amdgcn_mfma_f32_16x16x32_bf16(a1[mt][3], bf3, c, 0, 0, 0);
#pragma unroll
            for (int r = 0; r < 4; ++r) {
                int row = mt * 16 + q * 4 + r;
                h3_s[row * HS + fo] = f2b(fmaxf(c[r] + bb, 0.f));
            }
        }
    }
    __syncthreads();
    // phase-2 A-frags: 2 m-tiles x 7 k-steps (K pad 216->224; cols 216..223 are 0)
    bf16x8 a2[2][7];
#pragma unroll
    for (int mt = 0; mt < 2; ++mt)
#pragma unroll
        for (int ks = 0; ks < 7; ++ks)
            a2[mt][ks] = *(const bf16x8*)(h3_s + (mt * 16 + m) * HS + ks * 32 + q * 8);
    // phase 2: out(200) = h3 @ Wf + bf -> dense batch scatter; 8 waves cover nt 0..12
    for (int nt = wv; nt < 13; nt += 8) {
        const unsigned short* bp = Wfs + ((size_t)(nt * 7) * 64 + lane) * 8;
        bf16x8 bfr[7];
#pragma unroll
        for (int ks = 0; ks < 7; ++ks) bfr[ks] = *(const bf16x8*)(bp + ks * 512);
        int fo = nt * 16 + m;
        if (fo >= 200) continue;
        float bb = bfv[fo];
#pragma unroll
        for (int mt = 0; mt < 2; ++mt) {
            floatx4 c = {0.f, 0.f, 0.f, 0.f};
#pragma unroll
            for (int ks = 0; ks < 7; ++ks)
                c = __builtin_amdgcn_mfma_f32_16x16x32_bf16(a2[mt][ks], bfr[ks], c, 0, 0, 0);
#pragma unroll
            for (int r = 0; r < 4; ++r) {
                int n = node0 + mt * 16 + q * 4 + r;
                if (n < N) {
                    int b = batch[n];
                    int pos = n - gstarts[b];
                    if (pos >= 0 && pos < mn)
                        out[((size_t)b * mn + pos) * 200 + fo] = c[r] + bb;
                }
            }
        }
    }
}

extern "C" void kernel_launch(void* const* d_in, const int* in_sizes, int n_in,
                              void* d_out, int out_size, void* d_ws, size_t ws_size,
                              hipStream_t stream) {
    const float* x = (const float*)d_in[0];
    const int* ei = (const int*)d_in[1];
    const int* batch = (const int*)d_in[2];
    const float* W1 = (const float*)d_in[4];
    const float* b1 = (const float*)d_in[5];
    const float* W2 = (const float*)d_in[6];
    const float* b2 = (const float*)d_in[7];
    const float* W3 = (const float*)d_in[8];
    const float* b3 = (const float*)d_in[9];
    const float* Wf = (const float*)d_in[10];
    const float* bfv = (const float*)d_in[11];
    float* out = (float*)d_out;

    const int N = in_sizes[2];      // 50000
    const int E = in_sizes[1] / 2;  // 800000
    const int mn = out_size / (N_GRAPHS * 200);  // max_num = 1000
    const int* src = ei;
    const int* dst = ei + E;

    char* w = (char*)d_ws;  // ws is 256 MiB (observed via harness poison fills)
    auto alloc = [&](size_t bytes) {
        void* p = (void*)w;
        w += (bytes + 255) & ~(size_t)255;
        return p;
    };
    int* deg = (int*)alloc((size_t)N * 4);
    int* row_start = (int*)alloc((size_t)(N + 1) * 4);
    int* blk_sums = (int*)alloc(256 * 4);
    int* blk_off = (int*)alloc(256 * 4);
    int* cursor = (int*)alloc((size_t)N * 4);
    int2* col2 = (int2*)alloc((size_t)E * 8);
    float* dinv = (float*)alloc((size_t)N * 4);
    int* gstarts = (int*)alloc((N_GRAPHS + 1) * 4);
    unsigned short* xb = (unsigned short*)alloc((size_t)N * 64 * 2);   // padded, line-aligned
    unsigned short* h1 = (unsigned short*)alloc((size_t)N * 64 * 2);   // padded
    unsigned short* h2 = (unsigned short*)alloc((size_t)N * 128 * 2);  // padded
    unsigned short* W1s = (unsigned short*)alloc((size_t)T_W1 * 2);
    unsigned short* W2s = (unsigned short*)alloc((size_t)T_W2 * 2);
    unsigned short* W3s = (unsigned short*)alloc((size_t)T_W3 * 2);
    unsigned short* Wfs = (unsigned short*)alloc((size_t)T_WF * 2);
    (void)ws_size;

    hipMemsetAsync(deg, 0, (size_t)N * 4, stream);
    hipMemsetAsync(d_out, 0, (size_t)out_size * sizeof(float), stream);

    int NB = (N + 255) / 256;  // 196 <= 256, single-level block scan OK
    k_deg<<<(E + 255) / 256, 256, 0, stream>>>(dst, deg, E);
    k_scan_blocks<<<NB, 256, 0, stream>>>(deg, row_start, blk_sums, N);
    k_scan_tot<<<1, 256, 0, stream>>>(blk_sums, NB, blk_off);
    k_scan_add<<<NB, 256, 0, stream>>>(row_start, blk_off, cursor, deg, dinv, batch, gstarts,
                                       N, E);
    k_fill<<<(E + 255) / 256, 256, 0, stream>>>(src, dst, cursor, col2, dinv, E);
    int prep_total = T_W1 + T_W2 + T_W3 + T_WF + N * 64;
    k_prep<<<(prep_total + 255) / 256, 256, 0, stream>>>(W1, W2, W3, Wf, W1s, W2s, W3s, Wfs,
                                                         x, xb, N);

    int NBL16 = (N + 15) / 16;  // 3125 blocks x 4 waves
    // layer 1: gather(xb, 64p) -> MFMA @W1 -> h1[64p]
    k_layer<64, 54, 64, 2, 4><<<NBL16, 256, 0, stream>>>(xb, row_start, col2, dinv, W1s, b1,
                                                         h1, N);
    // layer 2: gather(h1, 64p) -> MFMA @W2 -> h2[128p]
    k_layer<64, 108, 128, 2, 8><<<NBL16, 256, 0, stream>>>(h1, row_start, col2, dinv, W2s,
                                                           b2, h2, N);
    int NBL32 = (N + 31) / 32;  // 1563 blocks x 8 waves
    // layer 3 + final: gather(h2, 128p) -> MFMA @W3 relu -> MFMA @Wf -> dense-batch scatter
    k_l3f<<<NBL32, 512, 0, stream>>>(h2, row_start, col2, dinv, W3s, b3, Wfs, bfv, batch,
                                     gstarts, out, N, mn);
}